// Round 10
// baseline (1538.218 us; speedup 1.0000x reference)
//
#include <hip/hip_runtime.h>
#include <math.h>

#define NB 32
#define LQ 784
#define LQP 832   // 13*64, padded sequence length for attention buffers
#define DIM 512
#define HEADS 8
#define MLP 2048
#define KPAD 448
#define MROWS 25088  // NB*LQ

typedef __attribute__((ext_vector_type(8))) short s8v;
typedef __attribute__((ext_vector_type(4))) short s4v;
typedef __attribute__((ext_vector_type(4))) float f4v;

__device__ __forceinline__ short f2b(float f){
  unsigned u = __builtin_bit_cast(unsigned, f);
  u = (u + 0x7fffu + ((u >> 16) & 1u)) >> 16;
  return (short)u;
}
__device__ __forceinline__ float b2f(short s){
  unsigned u = ((unsigned)(unsigned short)s) << 16;
  return __builtin_bit_cast(float, u);
}

// async global->LDS, 16B per lane. LDS dest pattern must be wave-uniform base + lane*16.
__device__ __forceinline__ void gll16(const short* g, short* l){
  __builtin_amdgcn_global_load_lds(
      (const __attribute__((address_space(1))) void*)g,
      (__attribute__((address_space(3))) void*)l, 16, 0, 0);
}

// T1: bijective XCD-aware remap (m204).
__device__ __forceinline__ void xcd_remap(int &bm, int &bn, int gx, int gy){
  int nwg = gx * gy;
  int flat = bm * gx + bn;
  int xcd = flat & 7, idx = flat >> 3;
  int q = nwg >> 3, r = nwg & 7;
  int nf = (xcd < r ? xcd * (q + 1) : r * (q + 1) + (xcd - r) * q) + idx;
  bm = nf / gx;
  bn = nf - bm * gx;
}

// ---------------- fused mask prep (single block) ----------------
__global__ __launch_bounds__(512) void mask_k(const int* __restrict__ done, float* __restrict__ keepL,
                                              int* __restrict__ kmask, int* __restrict__ liveg){
  __shared__ float keep[32][16];
  int tid = threadIdx.x;
  { int n = tid >> 4, t = tid & 15;
    int any = 0;
    for (int c = t; c < 15; ++c) any |= done[n*15 + c];
    keep[n][t] = any ? 0.f : 1.f; }
  __syncthreads();
  for (int i = tid; i < NB*LQP; i += 512){
    int n = i / LQP, l = i - n*LQP;
    keepL[i] = (l < LQ) ? keep[n][l/49] : 0.f;
  }
  if (tid < 32){
    int n = tid, m = 0;
    for (int kb = 0; kb < 13; ++kb){
      int t0 = (kb*64)/49, t1 = (kb*64 + 63)/49; if (t1 > 15) t1 = 15;
      float a = 0.f;
      for (int t = t0; t <= t1; ++t) a += keep[n][t];
      if (a > 0.5f) m |= 1 << kb;
    }
    kmask[n] = m;
  }
  for (int g = tid; g < 392; g += 512){
    float a = 0.f;
    for (int i2 = 0; i2 < 64; ++i2){
      int row = g*64 + i2;
      int n = row / 784, l = row - n*784;
      a += keep[n][l/49];
    }
    liveg[g] = a > 0.5f ? 1 : 0;
  }
}

// zero pad rows/cols once, vectorized s8v stores
__global__ __launch_bounds__(256) void zpad_k(short* __restrict__ Qb, short* __restrict__ Kb,
                                              short* __restrict__ Vtb){
  int idx = blockIdx.x*256 + threadIdx.x;   // < 294912
  s8v z;
  #pragma unroll
  for (int e=0;e<8;++e) z[e] = 0;
  if (idx < 98304){
    int nh = idx / 384, r = idx - nh*384;
    *(s8v*)(Qb + (long)nh*LQP*64 + 784*64 + r*8) = z;
  } else if (idx < 196608){
    int i2 = idx - 98304; int nh = i2 / 384, r = i2 - nh*384;
    *(s8v*)(Kb + (long)nh*LQP*64 + 784*64 + r*8) = z;
  } else {
    int i2 = idx - 196608; int nh = i2 / 384, rem = i2 - nh*384, d = rem/6, s = rem - d*6;
    *(s8v*)(Vtb + ((long)nh*64 + d)*LQP + 784 + s*8) = z;
  }
}

// Vm[nh*64+d] = mean over l<784 of V  (V^T layout)
__global__ __launch_bounds__(256) void vmean_k(const short* __restrict__ Vtb, float* __restrict__ Vm){
  int nh = blockIdx.x;
  int tid = threadIdx.x;
  int d = tid >> 2, seg = tid & 3;
  const short* row = Vtb + ((long)nh*64 + d)*LQP;
  float s = 0.f;
  for (int c = seg; c < 98; c += 4){
    s8v v = *(const s8v*)(row + c*8);
    #pragma unroll
    for (int e=0;e<8;++e) s += b2f(v[e]);
  }
  s += __shfl_xor(s, 1, 64);
  s += __shfl_xor(s, 2, 64);
  if (seg == 0) Vm[nh*64 + d] = s * (1.0f/784.0f);
}

// ---------------- patch pad+cast: 8 elems/thread, vectorized ----------------
#define PB0 5488   // 25088 rows * 56 chunks / 256
__global__ __launch_bounds__(256) void prep_k(
    const float* __restrict__ patch, short* __restrict__ patchb){
  int unit = blockIdx.x*256 + threadIdx.x;   // < 1404928
  int r = unit / 56, c8 = unit - r*56;
  s8v o;
  if (c8 < 54){
    const float* src = patch + (long)r*432 + c8*8;
    float4 a = *(const float4*)src;
    float4 b = *(const float4*)(src + 4);
    o[0]=f2b(a.x); o[1]=f2b(a.y); o[2]=f2b(a.z); o[3]=f2b(a.w);
    o[4]=f2b(b.x); o[5]=f2b(b.y); o[6]=f2b(b.z); o[7]=f2b(b.w);
  } else {
    #pragma unroll
    for (int e=0;e<8;++e) o[e] = 0;
  }
  *(s8v*)(patchb + (long)r*KPAD + c8*8) = o;
}

// ---------------- coalesced tiled weight transpose + optional LN-gamma fold ----------------
// fp32 [R][C] -> bf16 [C][Rpad]; dst[n][k] = g[k]*W[k][n] when g != nullptr.
__device__ __forceinline__ void tile_tr(const float* __restrict__ src, short* __restrict__ dst,
                                        int R, int C, int Rpad, int tr, int tc, int tid,
                                        float (*tile)[65], const float* __restrict__ g){
  int r0 = tr*64, c0 = tc*64;
  int w = tid >> 6, lane = tid & 63;
  #pragma unroll
  for (int p = 0; p < 16; ++p){
    int r = r0 + p*4 + w;
    float gv = (g && r < R) ? g[r] : 1.f;
    tile[p*4 + w][lane] = (r < R) ? gv * src[(long)r*C + c0 + lane] : 0.f;
  }
  __syncthreads();
  #pragma unroll
  for (int p = 0; p < 16; ++p){
    int cc = p*4 + w;
    dst[(long)(c0 + cc)*Rpad + r0 + lane] = f2b(tile[lane][cc]);
  }
}

// block ranges: Wemb 56 | Wqkv 768 | Wo 256 | W1 1024 | W2 1024  -> total 3128
__global__ __launch_bounds__(256) void trans_k(
    const float* __restrict__ Wemb, short* __restrict__ Wembt,
    const float* __restrict__ Wqkv, short* __restrict__ Wqkvt,
    const float* __restrict__ Wo,  short* __restrict__ Wot,
    const float* __restrict__ W1,  short* __restrict__ W1t,
    const float* __restrict__ W2,  short* __restrict__ W2t,
    const float* __restrict__ ln1_g, const float* __restrict__ ln2_g){
  __shared__ float tile[64][65];
  int b = blockIdx.x, tid = threadIdx.x;
  if (b < 56){
    int tr = b >> 3, tc = b & 7;                       // 7 x 8
    tile_tr(Wemb, Wembt, 432, 512, 448, tr, tc, tid, tile, nullptr);
  } else if (b < 56 + 768){
    int i = b - 56; int z = i / 192, rem = i - z*192;  // 8 x 24
    int tr = rem / 24, tc = rem - tr*24;
    tile_tr(Wqkv + (long)z*512*1536, Wqkvt + (long)z*1536*512, 512, 1536, 512, tr, tc, tid, tile,
            ln1_g + z*512);
  } else if (b < 56 + 768 + 256){
    int i = b - 824; int z = i >> 6, rem = i & 63;     // 8 x 8
    int tr = rem >> 3, tc = rem & 7;
    tile_tr(Wo + (long)z*512*512, Wot + (long)z*512*512, 512, 512, 512, tr, tc, tid, tile, nullptr);
  } else if (b < 56 + 768 + 256 + 1024){
    int i = b - 1080; int z = i >> 8, rem = i & 255;   // 8 x 32
    int tr = rem >> 5, tc = rem & 31;
    tile_tr(W1 + (long)z*512*2048, W1t + (long)z*2048*512, 512, 2048, 512, tr, tc, tid, tile,
            ln2_g + z*512);
  } else {
    int i = b - 2104; int z = i >> 8, rem = i & 255;   // 32 x 8
    int tr = rem >> 3, tc = rem & 7;
    tile_tr(W2 + (long)z*2048*512, W2t + (long)z*512*2048, 2048, 512, 2048, tr, tc, tid, tile, nullptr);
  }
}

// ---------------- LN-fold constant vectors: c1[n]=Sum_k g[k]W[k,n], cb[n]=Sum_k b[k]W[k,n]+bias[n]
__global__ __launch_bounds__(256) void cvec_k(
    const float* __restrict__ Wqkv, const float* __restrict__ bqkv,
    const float* __restrict__ ln1_g, const float* __restrict__ ln1_b,
    const float* __restrict__ W1, const float* __restrict__ b1,
    const float* __restrict__ ln2_g, const float* __restrict__ ln2_b,
    float* __restrict__ c1qkv, float* __restrict__ cbqkv,
    float* __restrict__ c1w1, float* __restrict__ cbw1){
  int b = blockIdx.x, tid = threadIdx.x;
  if (b < 24){                      // QKV: 4 layers x 6 blocks
    int z = b / 6, n = (b - z*6)*256 + tid;
    const float* W = Wqkv + (long)z*512*1536;
    const float* g = ln1_g + z*512; const float* bb = ln1_b + z*512;
    float c1 = 0.f, c2 = 0.f;
    #pragma unroll 4
    for (int k = 0; k < 512; ++k){
      float w = W[(long)k*1536 + n];
      c1 += g[k]*w; c2 += bb[k]*w;
    }
    c1qkv[z*1536 + n] = c1;
    cbqkv[z*1536 + n] = c2 + bqkv[z*1536 + n];
  } else {                          // W1: 4 layers x 8 blocks
    int i = b - 24; int z = i / 8, n = (i - z*8)*256 + tid;
    const float* W = W1 + (long)z*512*2048;
    const float* g = ln2_g + z*512; const float* bb = ln2_b + z*512;
    float c1 = 0.f, c2 = 0.f;
    #pragma unroll 4
    for (int k = 0; k < 512; ++k){
      float w = W[(long)k*2048 + n];
      c1 += g[k]*w; c2 += bb[k]*w;
    }
    c1w1[z*2048 + n] = c1;
    cbw1[z*2048 + n] = c2 + b1[z*2048 + n];
  }
}

// ---------------- per-row stats of bf16 shadow: mi[row] = (mean, rsqrt(var+eps)) ----------------
__global__ __launch_bounds__(256) void stats_k(const short* __restrict__ xb, float2* __restrict__ mi){
  int lane = threadIdx.x & 63;
  long row = (long)blockIdx.x * 4 + (threadIdx.x >> 6);
  s8v v = *(const s8v*)(xb + row*DIM + lane*8);
  float s = 0.f, q = 0.f;
  #pragma unroll
  for (int e=0;e<8;++e){ float f = b2f(v[e]); s += f; q += f*f; }
  #pragma unroll
  for (int m=1;m<64;m<<=1){ s += __shfl_xor(s,m,64); q += __shfl_xor(q,m,64); }
  if (lane == 0){
    float m = s * (1.0f/DIM);
    float var = q * (1.0f/DIM) - m*m;
    mi[row] = make_float2(m, rsqrtf(var + 1e-5f));
  }
}

// ---------------- final layernorm (fp32 x) ----------------
__global__ __launch_bounds__(256) void ln_k(const float* __restrict__ x, const float* __restrict__ g,
                                            const float* __restrict__ b, float* __restrict__ outf){
  int lane = threadIdx.x & 63;
  long row = (long)blockIdx.x * 4 + (threadIdx.x >> 6);
  const float* xr = x + row * DIM + lane * 8;
  float va[8];
  { float4 t0 = *(const float4*)xr; float4 t1 = *(const float4*)(xr + 4);
    va[0]=t0.x; va[1]=t0.y; va[2]=t0.z; va[3]=t0.w;
    va[4]=t1.x; va[5]=t1.y; va[6]=t1.z; va[7]=t1.w; }
  float s = 0.f, q = 0.f;
  #pragma unroll
  for (int j=0;j<8;++j){ s += va[j]; q += va[j]*va[j]; }
  #pragma unroll
  for (int m=1;m<64;m<<=1){ s += __shfl_xor(s,m,64); q += __shfl_xor(q,m,64); }
  float mean = s * (1.0f/DIM);
  float var = q * (1.0f/DIM) - mean*mean;
  float inv = rsqrtf(var + 1e-5f);
  int cb = lane*8;
  float4 t0, t1;
  t0.x=(va[0]-mean)*inv*g[cb+0]+b[cb+0]; t0.y=(va[1]-mean)*inv*g[cb+1]+b[cb+1];
  t0.z=(va[2]-mean)*inv*g[cb+2]+b[cb+2]; t0.w=(va[3]-mean)*inv*g[cb+3]+b[cb+3];
  t1.x=(va[4]-mean)*inv*g[cb+4]+b[cb+4]; t1.y=(va[5]-mean)*inv*g[cb+5]+b[cb+5];
  t1.z=(va[6]-mean)*inv*g[cb+6]+b[cb+6]; t1.w=(va[7]-mean)*inv*g[cb+7]+b[cb+7];
  *(float4*)(outf + row*DIM + cb) = t0;
  *(float4*)(outf + row*DIM + cb + 4) = t1;
}

// ---------------- GEMM, r2/r6 proven schedule; LN-folded epilogues for EPI 1/3 ----------------
// EPI 1/3: out = iv[r]*acc - iv[r]*m[r]*c1[n] + cb[n]   (A = raw bf16 x, W has g folded)
// EPI 0/2: also maintain xb = bf16(x) shadow.
template<int EPI>
__global__ __launch_bounds__(256) void gemm_k(
    const short* __restrict__ A, const short* __restrict__ Bt,
    const float* __restrict__ bias, int K, int N,
    float* __restrict__ xres, short* __restrict__ outb,
    const float* __restrict__ sp, const float* __restrict__ tp,
    short* __restrict__ Qb, short* __restrict__ Kb, short* __restrict__ Vtb,
    const int* __restrict__ liveg,
    const float2* __restrict__ mi, const float* __restrict__ c1v,
    short* __restrict__ xb)
{
  __shared__ __align__(16) short lA[2][128*64];
  __shared__ __align__(16) short lB[2][128*64];
  int bm = blockIdx.y, bn = blockIdx.x;
  xcd_remap(bm, bn, gridDim.x, gridDim.y);
  if (EPI == 1){
    if (bn < 8 && liveg[2*bm] == 0 && liveg[2*bm+1] == 0) return;
  }
  int tid = threadIdx.x;
  int lane = tid & 63, wid = tid >> 6;
  int col = lane & 15, quad = lane >> 4;
  int wm = (wid >> 1) * 64, wn = (wid & 1) * 64;
  f4v acc[4][4];
  #pragma unroll
  for (int i=0;i<4;++i)
    #pragma unroll
    for (int j=0;j<4;++j)
      #pragma unroll
      for (int e=0;e<4;++e) acc[i][j][e] = 0.0f;
  const short* Abase = A + (long)bm*128*K;
  const short* Bbase = Bt + (long)bn*128*K;
  int nt = K >> 6;
  #pragma unroll
  for (int c = 0; c < 4; ++c){
    int v = c*256 + tid;
    int r = v >> 3, j = v & 7;
    int kc = (j ^ (r & 7)) * 8;
    gll16(Abase + (long)r*K + kc, lA[0] + v*8);
    gll16(Bbase + (long)r*K + kc, lB[0] + v*8);
  }
  for (int t = 0; t < nt; ++t){
    int cur = t & 1;
    __builtin_amdgcn_s_barrier();
    __builtin_amdgcn_sched_barrier(0);
    if (t + 1 < nt){
      int kt = (t + 1) << 6;
      #pragma unroll
      for (int c = 0; c < 4; ++c){
        int v = c*256 + tid;
        int r = v >> 3, j = v & 7;
        int kc = (j ^ (r & 7)) * 8;
        gll16(Abase + (long)r*K + kt + kc, lA[cur^1] + v*8);
        gll16(Bbase + (long)r*K + kt + kc, lB[cur^1] + v*8);
      }
      asm volatile("s_waitcnt vmcnt(8)" ::: "memory");
    } else {
      asm volatile("s_waitcnt vmcnt(0)" ::: "memory");
    }
    __builtin_amdgcn_s_barrier();
    __builtin_amdgcn_sched_barrier(0);
    __builtin_amdgcn_s_setprio(1);
    #pragma unroll
    for (int ks = 0; ks < 2; ++ks){
      s8v af[4], bf[4];
      #pragma unroll
      for (int j=0;j<4;++j)
        af[j] = *(const s8v*)&lA[cur][(wm + j*16 + col)*64 + (((ks*4+quad) ^ (col&7)))*8];
      #pragma unroll
      for (int i=0;i<4;++i)
        bf[i] = *(const s8v*)&lB[cur][(wn + i*16 + col)*64 + (((ks*4+quad) ^ (col&7)))*8];
      #pragma unroll
      for (int i=0;i<4;++i)
        #pragma unroll
        for (int j=0;j<4;++j)
          acc[i][j] = __builtin_amdgcn_mfma_f32_16x16x32_bf16(bf[i], af[j], acc[i][j], 0, 0, 0);
    }
    __builtin_amdgcn_s_setprio(0);
    __builtin_amdgcn_sched_barrier(0);
  }
  // ---- V-block epilogue (QKV, bn>=8): folded correction + LDS transpose -> coalesced stores ----
  if (EPI == 1 && bn >= 8){
    __syncthreads();
    short* scr = &lA[0][0];                // [d_local 128][l_local 128]
    float2 mvv[4];
    #pragma unroll
    for (int j=0;j<4;++j) mvv[j] = mi[bm*128 + wm + j*16 + col];
    #pragma unroll
    for (int i=0;i<4;++i){
      int dl = wn + i*16 + quad*4;
      int gc0 = bn*128 + dl;
      float4 c14 = *(const float4*)(c1v + gc0);
      float4 cb4 = *(const float4*)(bias + gc0);
      #pragma unroll
      for (int j=0;j<4;++j){
        int ll = wm + j*16 + col;
        float s = mvv[j].y, tc = -mvv[j].x*mvv[j].y;
        scr[(dl+0)*128 + ll] = f2b(s*acc[i][j][0] + tc*c14.x + cb4.x);
        scr[(dl+1)*128 + ll] = f2b(s*acc[i][j][1] + tc*c14.y + cb4.y);
        scr[(dl+2)*128 + ll] = f2b(s*acc[i][j][2] + tc*c14.z + cb4.z);
        scr[(dl+3)*128 + ll] = f2b(s*acc[i][j][3] + tc*c14.w + cb4.w);
      }
    }
    __syncthreads();
    #pragma unroll
    for (int u=0;u<8;++u){
      int unit = u*256 + tid;
      int d = unit >> 4, c = unit & 15;
      int grow0 = bm*128 + c*8;
      int n2 = grow0 / LQ, l2 = grow0 - n2*LQ;
      int hh = (bn - 8)*2 + (d >> 6);
      long row = ((long)(n2*HEADS + hh))*64 + (d & 63);
      *(s8v*)(Vtb + row*LQP + l2) = *(const s8v*)&scr[d*128 + c*8];
    }
    return;
  }
  #pragma unroll
  for (int j=0;j<4;++j){
    int grow = (int)bm*128 + wm + j*16 + col;
    int l = 0, t = 0, p = 0, n = 0;
    if (EPI == 0){ l = grow % LQ; t = l / 49; p = l - t*49; }
    if (EPI == 1){ n = grow / LQ; l = grow - n*LQ; }
    float s = 1.f, tc = 0.f;
    if (EPI == 1 || EPI == 3){ float2 mv = mi[grow]; s = mv.y; tc = -mv.x*mv.y; }
    #pragma unroll
    for (int i=0;i<4;++i){
      int gc0 = (int)bn*128 + wn + i*16 + quad*4;
      float4 b4 = *(const float4*)(bias + gc0);
      float v0, v1, v2, v3;
      if (EPI == 1 || EPI == 3){
        float4 c14 = *(const float4*)(c1v + gc0);
        v0 = s*acc[i][j][0] + tc*c14.x + b4.x;
        v1 = s*acc[i][j][1] + tc*c14.y + b4.y;
        v2 = s*acc[i][j][2] + tc*c14.z + b4.z;
        v3 = s*acc[i][j][3] + tc*c14.w + b4.w;
      } else {
        v0 = acc[i][j][0] + b4.x;
        v1 = acc[i][j][1] + b4.y;
        v2 = acc[i][j][2] + b4.z;
        v3 = acc[i][j][3] + b4.w;
      }
      if (EPI == 0){
        float4 s4 = *(const float4*)(sp + p*DIM + gc0);
        float4 t4 = *(const float4*)(tp + t*DIM + gc0);
        float4 o; o.x = v0 + s4.x + t4.x; o.y = v1 + s4.y + t4.y;
        o.z = v2 + s4.z + t4.z; o.w = v3 + s4.w + t4.w;
        *(float4*)(xres + (long)grow*DIM + gc0) = o;
        s4v xo4; xo4[0]=f2b(o.x); xo4[1]=f2b(o.y); xo4[2]=f2b(o.z); xo4[3]=f2b(o.w);
        *(s4v*)(xb + (long)grow*DIM + gc0) = xo4;
      } else if (EPI == 1){
        if (gc0 < 512){
          int hh = gc0 >> 6, d0 = gc0 & 63;
          s4v o; o[0]=f2b(v0); o[1]=f2b(v1); o[2]=f2b(v2); o[3]=f2b(v3);
          *(s4v*)(Qb + (((long)(n*HEADS + hh))*LQP + l)*64 + d0) = o;
        } else {
          int c2 = gc0 - 512; int hh = c2 >> 6, d0 = c2 & 63;
          s4v o; o[0]=f2b(v0); o[1]=f2b(v1); o[2]=f2b(v2); o[3]=f2b(v3);
          *(s4v*)(Kb + (((long)(n*HEADS + hh))*LQP + l)*64 + d0) = o;
        }
      } else if (EPI == 2){
        float4 xo = *(const float4*)(xres + (long)grow*DIM + gc0);
        xo.x += v0; xo.y += v1; xo.z += v2; xo.w += v3;
        *(float4*)(xres + (long)grow*DIM + gc0) = xo;
        s4v xo4; xo4[0]=f2b(xo.x); xo4[1]=f2b(xo.y); xo4[2]=f2b(xo.z); xo4[3]=f2b(xo.w);
        *(s4v*)(xb + (long)grow*DIM + gc0) = xo4;
      } else if (EPI == 3){
        float g0 = v0 / (1.0f + __expf(-1.595769122f * v0 * (1.0f + 0.044715f*v0*v0)));
        float g1 = v1 / (1.0f + __expf(-1.595769122f * v1 * (1.0f + 0.044715f*v1*v1)));
        float g2 = v2 / (1.0f + __expf(-1.595769122f * v2 * (1.0f + 0.044715f*v2*v2)));
        float g3 = v3 / (1.0f + __expf(-1.595769122f * v3 * (1.0f + 0.044715f*v3*v3)));
        s4v o; o[0]=f2b(g0); o[1]=f2b(g1); o[2]=f2b(g2); o[3]=f2b(g3);
        *(s4v*)(outb + (long)grow*MLP + gc0) = o;
      }
    }
  }
}

// ---------------- sparse flash attention (unchanged) ----------------
__global__ __launch_bounds__(256) void attn_k(
    const short* __restrict__ Qb, const short* __restrict__ Kb,
    const short* __restrict__ Vtb, const float* __restrict__ keepL,
    const int* __restrict__ kmask, const float* __restrict__ Vm,
    short* __restrict__ Ob)
{
  __shared__ __align__(16) short lK[64*64];
  __shared__ __align__(16) short lV[64*64];
  __shared__ __align__(16) short lP[4][16*72];
  int tid = threadIdx.x;
  int lane = tid & 63, wid = tid >> 6;
  int col = lane & 15, quad = lane >> 4;
  int qb = blockIdx.x, h = blockIdx.y, n = blockIdx.z;
  long nh = (long)n*HEADS + h;
  int smask = kmask[n];
  int qr0 = qb*64 + wid*16;
  float vmv[4];
  #pragma unroll
  for (int j=0;j<4;++j) vmv[j] = Vm[nh*64 + j*16 + col];

  if (!((smask >> qb) & 1)){
    #pragma unroll
    for (int j=0;j<4;++j){
      short ov = f2b(vmv[j]);
      #pragma unroll
      for (int r=0;r<4;++r){
        int l = qr0 + quad*4 + r;
        if (l < LQ) Ob[((long)n*LQ + l)*DIM + h*64 + j*16 + col] = ov;
      }
    }
    return;
  }

  const float* kl = keepL + n*LQP;
  const short* qp = Qb + (nh*LQP + qr0 + col)*64 + quad*8;
  s8v aq0 = *(const s8v*)qp;
  s8v aq1 = *(const s8v*)(qp + 32);
  float keepA = kl[qr0 + col];
  if (keepA < 0.5f){
    #pragma unroll
    for (int e=0;e<8;++e){ aq0[e] = 0; aq1[e] = 0; }
  }
  float keepQ[4];
  #pragma unroll
  for (int r=0;r<4;++r) keepQ[r] = kl[qr0 + quad*4 + r];
  float kqs = keepQ[0] + keepQ[1] + keepQ[2] + keepQ[3];
  bool wlive = __ballot(kqs > 0.5f) != 0ull;
  float lsum[4] = {0.f,0.f,0.f,0.f};
  f4v Oacc[4];
  #pragma unroll
  for (int j=0;j<4;++j)
    #pragma unroll
    for (int e=0;e<4;++e) Oacc[j][e] = 0.0f;

  for (int kb = 0; kb < 13; ++kb){
    if (!((smask >> kb) & 1)) continue;
    int kbase = kb*64;
    __syncthreads();
    #pragma unroll
    for (int c = 0; c < 2; ++c){
      int v = c*256 + tid;
      int r = v >> 3, j = v & 7;
      int kc = (j ^ (r & 7)) * 8;
      gll16(Kb + (nh*LQP + kbase + r)*64 + kc, lK + v*8);
    }
    #pragma unroll
    for (int c = 0; c < 2; ++c){
      int v = c*256 + tid;
      int d = v >> 3, j = v & 7;
      int c8 = (j ^ (d & 7)) * 8;
      gll16(Vtb + (nh*64 + d)*LQP + kbase + c8, lV + v*8);
    }
    __syncthreads();
    if (!wlive) continue;
    float pm[4][4];
    #pragma unroll
    for (int ct = 0; ct < 4; ++ct){
      float keepK = kl[kbase + ct*16 + col];
      f4v s;
      #pragma unroll
      for (int e=0;e<4;++e) s[e] = 0.0f;
      #pragma unroll
      for (int ks = 0; ks < 2; ++ks){
        s8v bk = *(const s8v*)&lK[(ct*16 + col)*64 + (((ks*4+quad) ^ (col&7)))*8];
        if (keepK < 0.5f){
          #pragma unroll
          for (int e=0;e<8;++e) bk[e] = 0;
        }
        s = __builtin_amdgcn_mfma_f32_16x16x32_bf16(ks ? aq1 : aq0, bk, s, 0, 0, 0);
      }
      #pragma unroll
      for (int r=0;r<4;++r){
        float a = keepQ[r] * keepK;
        float t = fmaf(s[r], 0.125f, 10000.0f);
        float p = __expf(fmaf(a, t, -10000.0f));
        pm[ct][r] = p;
        lsum[r] += p;
      }
    }
    #pragma unroll
    for (int ct=0; ct<4; ++ct)
      #pragma unroll
      for (int r=0;r<4;++r)
        lP[wid][(quad*4 + r)*72 + ct*16 + col] = f2b(pm[ct][r]);
    #pragma unroll
    for (int j=0;j<4;++j){
      #pragma unroll
      for (int ks=0; ks<2; ++ks){
        s8v ap = *(const s8v*)&lP[wid][col*72 + ks*32 + quad*8];
        s8v bv = *(const s8v*)&lV[(j*16 + col)*64 + (((ks*4+quad) ^ (col&7)))*8];
        Oacc[j] = __builtin_amdgcn_mfma_f32_16x16x32_bf16(ap, bv, Oacc[j], 0, 0, 0);
      }
    }
  }
  #pragma unroll
  for (int m=1; m<16; m<<=1){
    #pragma unroll
    for (int r=0;r<4;++r) lsum[r] += __shfl_xor(lsum[r], m, 64);
  }
  float invl[4];
  #pragma unroll
  for (int r=0;r<4;++r) invl[r] = 1.0f / lsum[r];
  #pragma unroll
  for (int j=0;j<4;++j)
    #pragma unroll
    for (int r=0;r<4;++r){
      int l = qr0 + quad*4 + r;
      if (l < LQ){
        float val = keepQ[r] > 0.5f ? Oacc[j][r] * invl[r] : vmv[j];
        Ob[((long)n*LQ + l)*DIM + h*64 + j*16 + col] = f2b(val);
      }
    }
}

// ---------------- host ----------------
extern "C" void kernel_launch(void* const* d_in, const int* in_sizes, int n_in,
                              void* d_out, int out_size, void* d_ws, size_t ws_size,
                              hipStream_t stream) {
  const float* patch    = (const float*)d_in[0];
  const int*   done     = (const int*)d_in[1];
  const float* W_embed  = (const float*)d_in[2];
  const float* b_embed  = (const float*)d_in[3];
  const float* spatial  = (const float*)d_in[4];
  const float* temporal = (const float*)d_in[5];
  const float* ln1_g    = (const float*)d_in[6];
  const float* ln1_b    = (const float*)d_in[7];
  const float* Wqkv     = (const float*)d_in[8];
  const float* bqkv     = (const float*)d_in[9];
  const float* Wo       = (const float*)d_in[10];
  const float* bo       = (const float*)d_in[11];
  const float* ln2_g    = (const float*)d_in[12];
  const float* ln2_b    = (const float*)d_in[13];
  const float* W1       = (const float*)d_in[14];
  const float* b1       = (const float*)d_in[15];
  const float* W2       = (const float*)d_in[16];
  const float* b2       = (const float*)d_in[17];
  const float* out_g    = (const float*)d_in[18];
  const float* out_b    = (const float*)d_in[19];
  float* out = (float*)d_out;

  char* ws = (char*)d_ws;
  size_t off = 0;
  auto alloc = [&](size_t bytes)->char*{ char* p = ws + off; off += (bytes + 255) & ~(size_t)255; return p; };
  const size_t QKV_B = (size_t)NB*HEADS*LQP*64*2;
  float* x    = (float*)alloc((size_t)MROWS*DIM*4);
  short* xb   = (short*)alloc((size_t)MROWS*DIM*2);   // bf16 shadow of x
  short* hbuf = (short*)alloc((size_t)MROWS*DIM*2);   // attn output
  char*  U    = alloc((size_t)MROWS*MLP*2);
  short* patchb = (short*)U;
  short* Qb   = (short*)U;
  short* Kbf  = (short*)(U + QKV_B);
  short* Vtb  = (short*)(U + 2*QKV_B);
  short* obuf = hbuf;
  short* mid  = (short*)U;
  short* Wembt = (short*)alloc((size_t)512*448*2);
  short* Wqkvt = (short*)alloc((size_t)4*1536*512*2);
  short* Wot   = (short*)alloc((size_t)4*512*512*2);
  short* W1t   = (short*)alloc((size_t)4*2048*512*2);
  short* W2t   = (short*)alloc((size_t)4*512*2048*2);
  float* keepL = (float*)alloc((size_t)NB*LQP*4);
  int*   kmask = (int*)alloc(NB*4);
  int*   liveg = (int*)alloc(392*4);
  float* Vm    = (float*)alloc((size_t)NB*HEADS*64*4);
  float2* mi   = (float2*)alloc((size_t)MROWS*8);
  float* c1qkv = (float*)alloc((size_t)4*1536*4);
  float* cbqkv = (float*)alloc((size_t)4*1536*4);
  float* c1w1  = (float*)alloc((size_t)4*2048*4);
  float* cbw1  = (float*)alloc((size_t)4*2048*4);

  mask_k<<<1, 512, 0, stream>>>(done, keepL, kmask, liveg);
  prep_k<<<PB0, 256, 0, stream>>>(patch, patchb);
  trans_k<<<3128, 256, 0, stream>>>(W_embed, Wembt, Wqkv, Wqkvt, Wo, Wot, W1, W1t, W2, W2t,
                                    ln1_g, ln2_g);
  cvec_k<<<56, 256, 0, stream>>>(Wqkv, bqkv, ln1_g, ln1_b, W1, b1, ln2_g, ln2_b,
                                 c1qkv, cbqkv, c1w1, cbw1);

  gemm_k<0><<<dim3(DIM/128, MROWS/128), 256, 0, stream>>>(
      patchb, Wembt, b_embed, KPAD, DIM, x, nullptr, spatial, temporal,
      nullptr, nullptr, nullptr, nullptr, nullptr, nullptr, xb);

  zpad_k<<<1152, 256, 0, stream>>>(Qb, Kbf, Vtb);

  for (int i = 0; i < 4; ++i){
    stats_k<<<MROWS/4, 256, 0, stream>>>(xb, mi);
    gemm_k<1><<<dim3(1536/128, MROWS/128), 256, 0, stream>>>(
        xb, Wqkvt + (size_t)i*1536*512, cbqkv + (size_t)i*1536, DIM, 1536,
        nullptr, nullptr, nullptr, nullptr, Qb, Kbf, Vtb, liveg,
        mi, c1qkv + (size_t)i*1536, nullptr);
    vmean_k<<<NB*HEADS, 256, 0, stream>>>(Vtb, Vm);
    attn_k<<<dim3(13, HEADS, NB), 256, 0, stream>>>(Qb, Kbf, Vtb, keepL, kmask, Vm, obuf);
    gemm_k<2><<<dim3(DIM/128, MROWS/128), 256, 0, stream>>>(
        obuf, Wot + (size_t)i*512*512, bo + (size_t)i*DIM, DIM, DIM,
        x, nullptr, nullptr, nullptr, nullptr, nullptr, nullptr, nullptr,
        nullptr, nullptr, xb);
    stats_k<<<MROWS/4, 256, 0, stream>>>(xb, mi);
    gemm_k<3><<<dim3(MLP/128, MROWS/128), 256, 0, stream>>>(
        xb, W1t + (size_t)i*2048*512, cbw1 + (size_t)i*2048, DIM, MLP,
        nullptr, mid, nullptr, nullptr, nullptr, nullptr, nullptr, nullptr,
        mi, c1w1 + (size_t)i*2048, nullptr);
    gemm_k<2><<<dim3(DIM/128, MROWS/128), 256, 0, stream>>>(
        mid, W2t + (size_t)i*512*2048, b2 + (size_t)i*DIM, MLP, DIM,
        x, nullptr, nullptr, nullptr, nullptr, nullptr, nullptr, nullptr,
        nullptr, nullptr, xb);
  }
  ln_k<<<MROWS/4, 256, 0, stream>>>(x, out_g, out_b, out);
}

// Round 11
// 1480.474 us; speedup vs baseline: 1.0390x; 1.0390x over previous
//
#include <hip/hip_runtime.h>
#include <math.h>

#define NB 32
#define LQ 784
#define LQP 832   // 13*64, padded sequence length for attention buffers
#define DIM 512
#define HEADS 8
#define MLP 2048
#define KPAD 448
#define MROWS 25088  // NB*LQ

typedef __attribute__((ext_vector_type(8))) short s8v;
typedef __attribute__((ext_vector_type(4))) short s4v;
typedef __attribute__((ext_vector_type(4))) float f4v;

__device__ __forceinline__ short f2b(float f){
  unsigned u = __builtin_bit_cast(unsigned, f);
  u = (u + 0x7fffu + ((u >> 16) & 1u)) >> 16;
  return (short)u;
}
__device__ __forceinline__ float b2f(short s){
  unsigned u = ((unsigned)(unsigned short)s) << 16;
  return __builtin_bit_cast(float, u);
}

// async global->LDS, 16B per lane. LDS dest pattern must be wave-uniform base + lane*16.
__device__ __forceinline__ void gll16(const short* g, short* l){
  __builtin_amdgcn_global_load_lds(
      (const __attribute__((address_space(1))) void*)g,
      (__attribute__((address_space(3))) void*)l, 16, 0, 0);
}

// T1: bijective XCD-aware remap (m204).
__device__ __forceinline__ void xcd_remap(int &bm, int &bn, int gx, int gy){
  int nwg = gx * gy;
  int flat = bm * gx + bn;
  int xcd = flat & 7, idx = flat >> 3;
  int q = nwg >> 3, r = nwg & 7;
  int nf = (xcd < r ? xcd * (q + 1) : r * (q + 1) + (xcd - r) * q) + idx;
  bm = nf / gx;
  bn = nf - bm * gx;
}

// ---------------- fused mask prep (single block) ----------------
__global__ __launch_bounds__(512) void mask_k(const int* __restrict__ done, float* __restrict__ keepL,
                                              int* __restrict__ kmask, int* __restrict__ liveg){
  __shared__ float keep[32][16];
  int tid = threadIdx.x;
  { int n = tid >> 4, t = tid & 15;
    int any = 0;
    for (int c = t; c < 15; ++c) any |= done[n*15 + c];
    keep[n][t] = any ? 0.f : 1.f; }
  __syncthreads();
  for (int i = tid; i < NB*LQP; i += 512){
    int n = i / LQP, l = i - n*LQP;
    keepL[i] = (l < LQ) ? keep[n][l/49] : 0.f;
  }
  if (tid < 32){
    int n = tid, m = 0;
    for (int kb = 0; kb < 13; ++kb){
      int t0 = (kb*64)/49, t1 = (kb*64 + 63)/49; if (t1 > 15) t1 = 15;
      float a = 0.f;
      for (int t = t0; t <= t1; ++t) a += keep[n][t];
      if (a > 0.5f) m |= 1 << kb;
    }
    kmask[n] = m;
  }
  for (int g = tid; g < 392; g += 512){
    float a = 0.f;
    for (int i2 = 0; i2 < 64; ++i2){
      int row = g*64 + i2;
      int n = row / 784, l = row - n*784;
      a += keep[n][l/49];
    }
    liveg[g] = a > 0.5f ? 1 : 0;
  }
}

// zero pad rows/cols once, vectorized s8v stores
__global__ __launch_bounds__(256) void zpad_k(short* __restrict__ Qb, short* __restrict__ Kb,
                                              short* __restrict__ Vtb){
  int idx = blockIdx.x*256 + threadIdx.x;   // < 294912
  s8v z;
  #pragma unroll
  for (int e=0;e<8;++e) z[e] = 0;
  if (idx < 98304){
    int nh = idx / 384, r = idx - nh*384;
    *(s8v*)(Qb + (long)nh*LQP*64 + 784*64 + r*8) = z;
  } else if (idx < 196608){
    int i2 = idx - 98304; int nh = i2 / 384, r = i2 - nh*384;
    *(s8v*)(Kb + (long)nh*LQP*64 + 784*64 + r*8) = z;
  } else {
    int i2 = idx - 196608; int nh = i2 / 384, rem = i2 - nh*384, d = rem/6, s = rem - d*6;
    *(s8v*)(Vtb + ((long)nh*64 + d)*LQP + 784 + s*8) = z;
  }
}

// Vm[nh*64+d] = mean over l<784 of V  (V^T layout)
__global__ __launch_bounds__(256) void vmean_k(const short* __restrict__ Vtb, float* __restrict__ Vm){
  int nh = blockIdx.x;
  int tid = threadIdx.x;
  int d = tid >> 2, seg = tid & 3;
  const short* row = Vtb + ((long)nh*64 + d)*LQP;
  float s = 0.f;
  for (int c = seg; c < 98; c += 4){
    s8v v = *(const s8v*)(row + c*8);
    #pragma unroll
    for (int e=0;e<8;++e) s += b2f(v[e]);
  }
  s += __shfl_xor(s, 1, 64);
  s += __shfl_xor(s, 2, 64);
  if (seg == 0) Vm[nh*64 + d] = s * (1.0f/784.0f);
}

// ---------------- patch pad+cast: 8 elems/thread, vectorized ----------------
// KPAD = 448 = 56 chunks of 8; chunks 0..53 are data (432 = 54*8), 54..55 pure pad.
#define PB0 5488   // 25088 rows * 56 chunks / 256
__global__ __launch_bounds__(256) void prep_k(
    const float* __restrict__ patch, short* __restrict__ patchb){
  int unit = blockIdx.x*256 + threadIdx.x;   // < 1404928
  int r = unit / 56, c8 = unit - r*56;
  s8v o;
  if (c8 < 54){
    const float* src = patch + (long)r*432 + c8*8;
    float4 a = *(const float4*)src;
    float4 b = *(const float4*)(src + 4);
    o[0]=f2b(a.x); o[1]=f2b(a.y); o[2]=f2b(a.z); o[3]=f2b(a.w);
    o[4]=f2b(b.x); o[5]=f2b(b.y); o[6]=f2b(b.z); o[7]=f2b(b.w);
  } else {
    #pragma unroll
    for (int e=0;e<8;++e) o[e] = 0;
  }
  *(s8v*)(patchb + (long)r*KPAD + c8*8) = o;
}

// ---------------- coalesced tiled weight transpose: fp32 [R][C] -> bf16 [C][Rpad] ----------------
__device__ __forceinline__ void tile_tr(const float* __restrict__ src, short* __restrict__ dst,
                                        int R, int C, int Rpad, int tr, int tc, int tid,
                                        float (*tile)[65]){
  int r0 = tr*64, c0 = tc*64;
  int w = tid >> 6, lane = tid & 63;
  #pragma unroll
  for (int p = 0; p < 16; ++p){
    int r = r0 + p*4 + w;
    tile[p*4 + w][lane] = (r < R) ? src[(long)r*C + c0 + lane] : 0.f;
  }
  __syncthreads();
  #pragma unroll
  for (int p = 0; p < 16; ++p){
    int cc = p*4 + w;
    dst[(long)(c0 + cc)*Rpad + r0 + lane] = f2b(tile[lane][cc]);
  }
}

// block ranges: Wemb 56 | Wqkv 768 | Wo 256 | W1 1024 | W2 1024  -> total 3128
__global__ __launch_bounds__(256) void trans_k(
    const float* __restrict__ Wemb, short* __restrict__ Wembt,
    const float* __restrict__ Wqkv, short* __restrict__ Wqkvt,
    const float* __restrict__ Wo,  short* __restrict__ Wot,
    const float* __restrict__ W1,  short* __restrict__ W1t,
    const float* __restrict__ W2,  short* __restrict__ W2t){
  __shared__ float tile[64][65];
  int b = blockIdx.x, tid = threadIdx.x;
  if (b < 56){
    int tr = b >> 3, tc = b & 7;                       // 7 x 8
    tile_tr(Wemb, Wembt, 432, 512, 448, tr, tc, tid, tile);
  } else if (b < 56 + 768){
    int i = b - 56; int z = i / 192, rem = i - z*192;  // 8 x 24
    int tr = rem / 24, tc = rem - tr*24;
    tile_tr(Wqkv + (long)z*512*1536, Wqkvt + (long)z*1536*512, 512, 1536, 512, tr, tc, tid, tile);
  } else if (b < 56 + 768 + 256){
    int i = b - 824; int z = i >> 6, rem = i & 63;     // 8 x 8
    int tr = rem >> 3, tc = rem & 7;
    tile_tr(Wo + (long)z*512*512, Wot + (long)z*512*512, 512, 512, 512, tr, tc, tid, tile);
  } else if (b < 56 + 768 + 256 + 1024){
    int i = b - 1080; int z = i >> 8, rem = i & 255;   // 8 x 32
    int tr = rem >> 5, tc = rem & 31;
    tile_tr(W1 + (long)z*512*2048, W1t + (long)z*2048*512, 512, 2048, 512, tr, tc, tid, tile);
  } else {
    int i = b - 2104; int z = i >> 8, rem = i & 255;   // 32 x 8
    int tr = rem >> 3, tc = rem & 7;
    tile_tr(W2 + (long)z*2048*512, W2t + (long)z*512*2048, 2048, 512, 2048, tr, tc, tid, tile);
  }
}

// ---------------- layernorm: 1 wave per 512-wide row, 4 rows/block ----------------
__global__ __launch_bounds__(256) void ln_k(const float* __restrict__ x, const float* __restrict__ g,
                                            const float* __restrict__ b, short* __restrict__ outb,
                                            float* __restrict__ outf){
  int lane = threadIdx.x & 63;
  long row = (long)blockIdx.x * 4 + (threadIdx.x >> 6);
  const float* xr = x + row * DIM + lane * 8;
  float va[8];
  { float4 t0 = *(const float4*)xr; float4 t1 = *(const float4*)(xr + 4);
    va[0]=t0.x; va[1]=t0.y; va[2]=t0.z; va[3]=t0.w;
    va[4]=t1.x; va[5]=t1.y; va[6]=t1.z; va[7]=t1.w; }
  float s = 0.f, q = 0.f;
  #pragma unroll
  for (int j=0;j<8;++j){ s += va[j]; q += va[j]*va[j]; }
  #pragma unroll
  for (int m=1;m<64;m<<=1){ s += __shfl_xor(s,m,64); q += __shfl_xor(q,m,64); }
  float mean = s * (1.0f/DIM);
  float var = q * (1.0f/DIM) - mean*mean;
  float inv = rsqrtf(var + 1e-5f);
  int cb = lane*8;
  if (outb){
    s8v o;
    #pragma unroll
    for (int j=0;j<8;++j) o[j] = f2b((va[j]-mean)*inv*g[cb+j] + b[cb+j]);
    *(s8v*)(outb + row*DIM + cb) = o;
  } else {
    float4 t0, t1;
    t0.x=(va[0]-mean)*inv*g[cb+0]+b[cb+0]; t0.y=(va[1]-mean)*inv*g[cb+1]+b[cb+1];
    t0.z=(va[2]-mean)*inv*g[cb+2]+b[cb+2]; t0.w=(va[3]-mean)*inv*g[cb+3]+b[cb+3];
    t1.x=(va[4]-mean)*inv*g[cb+4]+b[cb+4]; t1.y=(va[5]-mean)*inv*g[cb+5]+b[cb+5];
    t1.z=(va[6]-mean)*inv*g[cb+6]+b[cb+6]; t1.w=(va[7]-mean)*inv*g[cb+7]+b[cb+7];
    *(float4*)(outf + row*DIM + cb) = t0;
    *(float4*)(outf + row*DIM + cb + 4) = t1;
  }
}

// ---------------- GEMM, r2/r6 proven schedule (LDS A+B, counted vmcnt, T1 remap) ----------------
template<int EPI>
__global__ __launch_bounds__(256) void gemm_k(
    const short* __restrict__ A, const short* __restrict__ Bt,
    const float* __restrict__ bias, int K, int N,
    float* __restrict__ xres, short* __restrict__ outb,
    const float* __restrict__ sp, const float* __restrict__ tp,
    short* __restrict__ Qb, short* __restrict__ Kb, short* __restrict__ Vtb,
    const int* __restrict__ liveg)
{
  __shared__ __align__(16) short lA[2][128*64];
  __shared__ __align__(16) short lB[2][128*64];
  int bm = blockIdx.y, bn = blockIdx.x;
  xcd_remap(bm, bn, gridDim.x, gridDim.y);
  if (EPI == 1){
    if (bn < 8 && liveg[2*bm] == 0 && liveg[2*bm+1] == 0) return;
  }
  int tid = threadIdx.x;
  int lane = tid & 63, wid = tid >> 6;
  int col = lane & 15, quad = lane >> 4;
  int wm = (wid >> 1) * 64, wn = (wid & 1) * 64;
  f4v acc[4][4];
  #pragma unroll
  for (int i=0;i<4;++i)
    #pragma unroll
    for (int j=0;j<4;++j)
      #pragma unroll
      for (int e=0;e<4;++e) acc[i][j][e] = 0.0f;
  const short* Abase = A + (long)bm*128*K;
  const short* Bbase = Bt + (long)bn*128*K;
  int nt = K >> 6;
  #pragma unroll
  for (int c = 0; c < 4; ++c){
    int v = c*256 + tid;
    int r = v >> 3, j = v & 7;
    int kc = (j ^ (r & 7)) * 8;
    gll16(Abase + (long)r*K + kc, lA[0] + v*8);
    gll16(Bbase + (long)r*K + kc, lB[0] + v*8);
  }
  for (int t = 0; t < nt; ++t){
    int cur = t & 1;
    __builtin_amdgcn_s_barrier();
    __builtin_amdgcn_sched_barrier(0);
    if (t + 1 < nt){
      int kt = (t + 1) << 6;
      #pragma unroll
      for (int c = 0; c < 4; ++c){
        int v = c*256 + tid;
        int r = v >> 3, j = v & 7;
        int kc = (j ^ (r & 7)) * 8;
        gll16(Abase + (long)r*K + kt + kc, lA[cur^1] + v*8);
        gll16(Bbase + (long)r*K + kt + kc, lB[cur^1] + v*8);
      }
      asm volatile("s_waitcnt vmcnt(8)" ::: "memory");
    } else {
      asm volatile("s_waitcnt vmcnt(0)" ::: "memory");
    }
    __builtin_amdgcn_s_barrier();
    __builtin_amdgcn_sched_barrier(0);
    __builtin_amdgcn_s_setprio(1);
    #pragma unroll
    for (int ks = 0; ks < 2; ++ks){
      s8v af[4], bf[4];
      #pragma unroll
      for (int j=0;j<4;++j)
        af[j] = *(const s8v*)&lA[cur][(wm + j*16 + col)*64 + (((ks*4+quad) ^ (col&7)))*8];
      #pragma unroll
      for (int i=0;i<4;++i)
        bf[i] = *(const s8v*)&lB[cur][(wn + i*16 + col)*64 + (((ks*4+quad) ^ (col&7)))*8];
      #pragma unroll
      for (int i=0;i<4;++i)
        #pragma unroll
        for (int j=0;j<4;++j)
          acc[i][j] = __builtin_amdgcn_mfma_f32_16x16x32_bf16(bf[i], af[j], acc[i][j], 0, 0, 0);
    }
    __builtin_amdgcn_s_setprio(0);
    __builtin_amdgcn_sched_barrier(0);
  }
  // ---- V-block epilogue (QKV, bn>=8): LDS transpose -> coalesced s8v stores ----
  if (EPI == 1 && bn >= 8){
    __syncthreads();                       // all waves done reading lA/lB
    short* scr = &lA[0][0];                // 32 KB scratch: [d_local 128][l_local 128]
    #pragma unroll
    for (int i=0;i<4;++i){
      int dl = wn + i*16 + quad*4;
      int gc0 = bn*128 + dl;
      float4 b4 = *(const float4*)(bias + gc0);
      #pragma unroll
      for (int j=0;j<4;++j){
        int ll = wm + j*16 + col;
        scr[(dl+0)*128 + ll] = f2b(acc[i][j][0] + b4.x);
        scr[(dl+1)*128 + ll] = f2b(acc[i][j][1] + b4.y);
        scr[(dl+2)*128 + ll] = f2b(acc[i][j][2] + b4.z);
        scr[(dl+3)*128 + ll] = f2b(acc[i][j][3] + b4.w);
      }
    }
    __syncthreads();
    #pragma unroll
    for (int u=0;u<8;++u){
      int unit = u*256 + tid;              // 2048 units: 128 d x 16 l-chunks
      int d = unit >> 4, c = unit & 15;
      int grow0 = bm*128 + c*8;            // 8-chunks never straddle n (784 % 8 == 0)
      int n2 = grow0 / LQ, l2 = grow0 - n2*LQ;
      int hh = (bn - 8)*2 + (d >> 6);
      long row = ((long)(n2*HEADS + hh))*64 + (d & 63);
      *(s8v*)(Vtb + row*LQP + l2) = *(const s8v*)&scr[d*128 + c*8];
    }
    return;
  }
  #pragma unroll
  for (int j=0;j<4;++j){
    int grow = (int)bm*128 + wm + j*16 + col;
    int l = 0, t = 0, p = 0, n = 0;
    if (EPI == 0){ l = grow % LQ; t = l / 49; p = l - t*49; }
    if (EPI == 1){ n = grow / LQ; l = grow - n*LQ; }
    #pragma unroll
    for (int i=0;i<4;++i){
      int gc0 = (int)bn*128 + wn + i*16 + quad*4;
      float4 b4 = *(const float4*)(bias + gc0);
      float v0 = acc[i][j][0] + b4.x;
      float v1 = acc[i][j][1] + b4.y;
      float v2 = acc[i][j][2] + b4.z;
      float v3 = acc[i][j][3] + b4.w;
      if (EPI == 0){
        float4 s4 = *(const float4*)(sp + p*DIM + gc0);
        float4 t4 = *(const float4*)(tp + t*DIM + gc0);
        float4 o; o.x = v0 + s4.x + t4.x; o.y = v1 + s4.y + t4.y;
        o.z = v2 + s4.z + t4.z; o.w = v3 + s4.w + t4.w;
        *(float4*)(xres + (long)grow*DIM + gc0) = o;
      } else if (EPI == 1){
        if (gc0 < 512){
          int hh = gc0 >> 6, d0 = gc0 & 63;
          s4v o; o[0]=f2b(v0); o[1]=f2b(v1); o[2]=f2b(v2); o[3]=f2b(v3);
          *(s4v*)(Qb + (((long)(n*HEADS + hh))*LQP + l)*64 + d0) = o;
        } else {
          int c2 = gc0 - 512; int hh = c2 >> 6, d0 = c2 & 63;
          s4v o; o[0]=f2b(v0); o[1]=f2b(v1); o[2]=f2b(v2); o[3]=f2b(v3);
          *(s4v*)(Kb + (((long)(n*HEADS + hh))*LQP + l)*64 + d0) = o;
        }
      } else if (EPI == 2){
        float4 xo = *(const float4*)(xres + (long)grow*DIM + gc0);
        xo.x += v0; xo.y += v1; xo.z += v2; xo.w += v3;
        *(float4*)(xres + (long)grow*DIM + gc0) = xo;
      } else if (EPI == 3){
        float g0 = v0 / (1.0f + __expf(-1.595769122f * v0 * (1.0f + 0.044715f*v0*v0)));
        float g1 = v1 / (1.0f + __expf(-1.595769122f * v1 * (1.0f + 0.044715f*v1*v1)));
        float g2 = v2 / (1.0f + __expf(-1.595769122f * v2 * (1.0f + 0.044715f*v2*v2)));
        float g3 = v3 / (1.0f + __expf(-1.595769122f * v3 * (1.0f + 0.044715f*v3*v3)));
        s4v o; o[0]=f2b(g0); o[1]=f2b(g1); o[2]=f2b(g2); o[3]=f2b(g3);
        *(s4v*)(outb + (long)grow*MLP + gc0) = o;
      }
    }
  }
}

// ---------------- sparse flash attention (unchanged) ----------------
__global__ __launch_bounds__(256) void attn_k(
    const short* __restrict__ Qb, const short* __restrict__ Kb,
    const short* __restrict__ Vtb, const float* __restrict__ keepL,
    const int* __restrict__ kmask, const float* __restrict__ Vm,
    short* __restrict__ Ob)
{
  __shared__ __align__(16) short lK[64*64];
  __shared__ __align__(16) short lV[64*64];
  __shared__ __align__(16) short lP[4][16*72];
  int tid = threadIdx.x;
  int lane = tid & 63, wid = tid >> 6;
  int col = lane & 15, quad = lane >> 4;
  int qb = blockIdx.x, h = blockIdx.y, n = blockIdx.z;
  long nh = (long)n*HEADS + h;
  int smask = kmask[n];
  int qr0 = qb*64 + wid*16;
  float vmv[4];
  #pragma unroll
  for (int j=0;j<4;++j) vmv[j] = Vm[nh*64 + j*16 + col];

  if (!((smask >> qb) & 1)){
    #pragma unroll
    for (int j=0;j<4;++j){
      short ov = f2b(vmv[j]);
      #pragma unroll
      for (int r=0;r<4;++r){
        int l = qr0 + quad*4 + r;
        if (l < LQ) Ob[((long)n*LQ + l)*DIM + h*64 + j*16 + col] = ov;
      }
    }
    return;
  }

  const float* kl = keepL + n*LQP;
  const short* qp = Qb + (nh*LQP + qr0 + col)*64 + quad*8;
  s8v aq0 = *(const s8v*)qp;
  s8v aq1 = *(const s8v*)(qp + 32);
  float keepA = kl[qr0 + col];
  if (keepA < 0.5f){
    #pragma unroll
    for (int e=0;e<8;++e){ aq0[e] = 0; aq1[e] = 0; }
  }
  float keepQ[4];
  #pragma unroll
  for (int r=0;r<4;++r) keepQ[r] = kl[qr0 + quad*4 + r];
  float kqs = keepQ[0] + keepQ[1] + keepQ[2] + keepQ[3];
  bool wlive = __ballot(kqs > 0.5f) != 0ull;
  float lsum[4] = {0.f,0.f,0.f,0.f};
  f4v Oacc[4];
  #pragma unroll
  for (int j=0;j<4;++j)
    #pragma unroll
    for (int e=0;e<4;++e) Oacc[j][e] = 0.0f;

  for (int kb = 0; kb < 13; ++kb){
    if (!((smask >> kb) & 1)) continue;
    int kbase = kb*64;
    __syncthreads();
    #pragma unroll
    for (int c = 0; c < 2; ++c){
      int v = c*256 + tid;
      int r = v >> 3, j = v & 7;
      int kc = (j ^ (r & 7)) * 8;
      gll16(Kb + (nh*LQP + kbase + r)*64 + kc, lK + v*8);
    }
    #pragma unroll
    for (int c = 0; c < 2; ++c){
      int v = c*256 + tid;
      int d = v >> 3, j = v & 7;
      int c8 = (j ^ (d & 7)) * 8;
      gll16(Vtb + (nh*64 + d)*LQP + kbase + c8, lV + v*8);
    }
    __syncthreads();
    if (!wlive) continue;
    float pm[4][4];
    #pragma unroll
    for (int ct = 0; ct < 4; ++ct){
      float keepK = kl[kbase + ct*16 + col];
      f4v s;
      #pragma unroll
      for (int e=0;e<4;++e) s[e] = 0.0f;
      #pragma unroll
      for (int ks = 0; ks < 2; ++ks){
        s8v bk = *(const s8v*)&lK[(ct*16 + col)*64 + (((ks*4+quad) ^ (col&7)))*8];
        if (keepK < 0.5f){
          #pragma unroll
          for (int e=0;e<8;++e) bk[e] = 0;
        }
        s = __builtin_amdgcn_mfma_f32_16x16x32_bf16(ks ? aq1 : aq0, bk, s, 0, 0, 0);
      }
      #pragma unroll
      for (int r=0;r<4;++r){
        float a = keepQ[r] * keepK;
        float t = fmaf(s[r], 0.125f, 10000.0f);
        float p = __expf(fmaf(a, t, -10000.0f));
        pm[ct][r] = p;
        lsum[r] += p;
      }
    }
    #pragma unroll
    for (int ct=0; ct<4; ++ct)
      #pragma unroll
      for (int r=0;r<4;++r)
        lP[wid][(quad*4 + r)*72 + ct*16 + col] = f2b(pm[ct][r]);
    #pragma unroll
    for (int j=0;j<4;++j){
      #pragma unroll
      for (int ks=0; ks<2; ++ks){
        s8v ap = *(const s8v*)&lP[wid][col*72 + ks*32 + quad*8];
        s8v bv = *(const s8v*)&lV[(j*16 + col)*64 + (((ks*4+quad) ^ (col&7)))*8];
        Oacc[j] = __builtin_amdgcn_mfma_f32_16x16x32_bf16(ap, bv, Oacc[j], 0, 0, 0);
      }
    }
  }
  #pragma unroll
  for (int m=1; m<16; m<<=1){
    #pragma unroll
    for (int r=0;r<4;++r) lsum[r] += __shfl_xor(lsum[r], m, 64);
  }
  float invl[4];
  #pragma unroll
  for (int r=0;r<4;++r) invl[r] = 1.0f / lsum[r];
  #pragma unroll
  for (int j=0;j<4;++j)
    #pragma unroll
    for (int r=0;r<4;++r){
      int l = qr0 + quad*4 + r;
      if (l < LQ){
        float val = keepQ[r] > 0.5f ? Oacc[j][r] * invl[r] : vmv[j];
        Ob[((long)n*LQ + l)*DIM + h*64 + j*16 + col] = f2b(val);
      }
    }
}

// ---------------- host ----------------
extern "C" void kernel_launch(void* const* d_in, const int* in_sizes, int n_in,
                              void* d_out, int out_size, void* d_ws, size_t ws_size,
                              hipStream_t stream) {
  const float* patch    = (const float*)d_in[0];
  const int*   done     = (const int*)d_in[1];
  const float* W_embed  = (const float*)d_in[2];
  const float* b_embed  = (const float*)d_in[3];
  const float* spatial  = (const float*)d_in[4];
  const float* temporal = (const float*)d_in[5];
  const float* ln1_g    = (const float*)d_in[6];
  const float* ln1_b    = (const float*)d_in[7];
  const float* Wqkv     = (const float*)d_in[8];
  const float* bqkv     = (const float*)d_in[9];
  const float* Wo       = (const float*)d_in[10];
  const float* bo       = (const float*)d_in[11];
  const float* ln2_g    = (const float*)d_in[12];
  const float* ln2_b    = (const float*)d_in[13];
  const float* W1       = (const float*)d_in[14];
  const float* b1       = (const float*)d_in[15];
  const float* W2       = (const float*)d_in[16];
  const float* b2       = (const float*)d_in[17];
  const float* out_g    = (const float*)d_in[18];
  const float* out_b    = (const float*)d_in[19];
  float* out = (float*)d_out;

  char* ws = (char*)d_ws;
  size_t off = 0;
  auto alloc = [&](size_t bytes)->char*{ char* p = ws + off; off += (bytes + 255) & ~(size_t)255; return p; };
  const size_t QKV_B = (size_t)NB*HEADS*LQP*64*2;
  float* x    = (float*)alloc((size_t)MROWS*DIM*4);
  short* hbuf = (short*)alloc((size_t)MROWS*DIM*2);
  char*  U    = alloc((size_t)MROWS*MLP*2);
  short* patchb = (short*)U;
  short* Qb   = (short*)U;
  short* Kbf  = (short*)(U + QKV_B);
  short* Vtb  = (short*)(U + 2*QKV_B);
  short* obuf = hbuf;
  short* mid  = (short*)U;
  short* Wembt = (short*)alloc((size_t)512*448*2);
  short* Wqkvt = (short*)alloc((size_t)4*1536*512*2);
  short* Wot   = (short*)alloc((size_t)4*512*512*2);
  short* W1t   = (short*)alloc((size_t)4*2048*512*2);
  short* W2t   = (short*)alloc((size_t)4*512*2048*2);
  float* keepL = (float*)alloc((size_t)NB*LQP*4);
  int*   kmask = (int*)alloc(NB*4);
  int*   liveg = (int*)alloc(392*4);
  float* Vm    = (float*)alloc((size_t)NB*HEADS*64*4);

  mask_k<<<1, 512, 0, stream>>>(done, keepL, kmask, liveg);
  prep_k<<<PB0, 256, 0, stream>>>(patch, patchb);
  trans_k<<<3128, 256, 0, stream>>>(W_embed, Wembt, Wqkv, Wqkvt, Wo, Wot, W1, W1t, W2, W2t);

  gemm_k<0><<<dim3(DIM/128, MROWS/128), 256, 0, stream>>>(
      patchb, Wembt, b_embed, KPAD, DIM, x, nullptr, spatial, temporal,
      nullptr, nullptr, nullptr, nullptr);

  zpad_k<<<1152, 256, 0, stream>>>(Qb, Kbf, Vtb);

  for (int i = 0; i < 4; ++i){
    ln_k<<<MROWS/4, 256, 0, stream>>>(x, ln1_g + i*DIM, ln1_b + i*DIM, hbuf, nullptr);
    gemm_k<1><<<dim3(1536/128, MROWS/128), 256, 0, stream>>>(
        hbuf, Wqkvt + (size_t)i*1536*512, bqkv + (size_t)i*1536, DIM, 1536,
        nullptr, nullptr, nullptr, nullptr, Qb, Kbf, Vtb, liveg);
    vmean_k<<<NB*HEADS, 256, 0, stream>>>(Vtb, Vm);
    attn_k<<<dim3(13, HEADS, NB), 256, 0, stream>>>(Qb, Kbf, Vtb, keepL, kmask, Vm, obuf);
    gemm_k<2><<<dim3(DIM/128, MROWS/128), 256, 0, stream>>>(
        obuf, Wot + (size_t)i*512*512, bo + (size_t)i*DIM, DIM, DIM,
        x, nullptr, nullptr, nullptr, nullptr, nullptr, nullptr, nullptr);
    ln_k<<<MROWS/4, 256, 0, stream>>>(x, ln2_g + i*DIM, ln2_b + i*DIM, hbuf, nullptr);
    gemm_k<3><<<dim3(MLP/128, MROWS/128), 256, 0, stream>>>(
        hbuf, W1t + (size_t)i*2048*512, b1 + (size_t)i*MLP, DIM, MLP,
        nullptr, mid, nullptr, nullptr, nullptr, nullptr, nullptr, nullptr);
    gemm_k<2><<<dim3(DIM/128, MROWS/128), 256, 0, stream>>>(
        mid, W2t + (size_t)i*512*2048, b2 + (size_t)i*DIM, MLP, DIM,
        x, nullptr, nullptr, nullptr, nullptr, nullptr, nullptr, nullptr);
  }
  ln_k<<<MROWS/4, 256, 0, stream>>>(x, out_g, out_b, nullptr, out);
}